// Round 1
// baseline (499.869 us; speedup 1.0000x reference)
//
#include <hip/hip_runtime.h>

#define HH 8
#define LL 256
#define CC 32
#define VT_STRIDE 264   // padded sk2 stride for V^T, 16B-aligned rows, spreads banks
#define P_STRIDE  264   // padded sk2 stride for P, 16B-aligned rows

typedef _Float16 f16x8 __attribute__((ext_vector_type(8)));
typedef _Float16 f16x4 __attribute__((ext_vector_type(4)));
typedef float    f32x4 __attribute__((ext_vector_type(4)));

// Transpose bias (B=1, s2, sk2, H) -> biasT [H][s2][sk2] so the main kernel's
// bias loads are lane-coalesced instead of stride-8 scatter.
__global__ __launch_bounds__(256)
void bias_transpose(const float* __restrict__ bias, float* __restrict__ biasT) {
    const int g = blockIdx.x * 256 + threadIdx.x;   // g = h*65536 + s2*256 + sk2
    const int h = g >> 16;
    const int s2sk2 = g & 65535;
    biasT[g] = bias[(s2sk2 << 3) | h];
}

__global__ __launch_bounds__(256, 2)
void triattn(const float* __restrict__ q, const float* __restrict__ k,
             const float* __restrict__ v, const float* __restrict__ bias,
             const float* __restrict__ biasT,   // may be null -> fallback path
             const float* __restrict__ gate, float* __restrict__ out) {
    __shared__ _Float16 Klds[LL * CC];            // [sk2][32]
    __shared__ _Float16 Vt[CC * VT_STRIDE];       // [c][sk2]
    __shared__ _Float16 Plds[4][16 * P_STRIDE];   // per-wave [row16][sk2]

    const int h    = blockIdx.y;
    const int s1   = blockIdx.x;
    const int tid  = threadIdx.x;
    const int wave = tid >> 6;
    const int lane = tid & 63;
    const int n16  = lane & 15;
    const int quad = lane >> 4;

    const size_t base = ((size_t)(h * LL + s1)) * (LL * CC);
    const float* qb = q + base;
    const float* kb = k + base;
    const float* vb = v + base;
    float*       ob = out + base;
    const float* gateb = gate + ((size_t)s1 * (LL * CC * HH)) + h;

    // ---- stage K and V^T into LDS as fp16 ----
    const float4* k4 = (const float4*)kb;
    const float4* v4 = (const float4*)vb;
    #pragma unroll
    for (int i = 0; i < 8; ++i) {
        const int idx = tid + i * 256;        // float4 index over 2048
        const int row = idx >> 3;             // sk2
        const int c0  = (idx & 7) * 4;        // channel base
        float4 f = k4[idx];
        f16x4 kv4 = { (_Float16)f.x, (_Float16)f.y, (_Float16)f.z, (_Float16)f.w };
        *(f16x4*)&Klds[row * CC + c0] = kv4;  // 8B store, aligned
        float4 g = v4[idx];
        _Float16* vd = &Vt[c0 * VT_STRIDE + row];
        vd[0]             = (_Float16)g.x;
        vd[VT_STRIDE]     = (_Float16)g.y;
        vd[2 * VT_STRIDE] = (_Float16)g.z;
        vd[3 * VT_STRIDE] = (_Float16)g.w;
    }
    __syncthreads();

    _Float16* pw = Plds[wave];

    #pragma unroll 1
    for (int si = 0; si < 4; ++si) {
        const int strip = wave * 4 + si;
        const int r0 = strip * 16;            // s2 base for this strip

        // Q A-fragment: A[m=lane&15][k=quad*8+j]
        f16x8 qf;
        {
            const float4* qr4 = (const float4*)(qb + (size_t)(r0 + n16) * CC + quad * 8);
            float4 a = qr4[0], b = qr4[1];
            qf[0] = (_Float16)a.x; qf[1] = (_Float16)a.y;
            qf[2] = (_Float16)a.z; qf[3] = (_Float16)a.w;
            qf[4] = (_Float16)b.x; qf[5] = (_Float16)b.y;
            qf[6] = (_Float16)b.z; qf[7] = (_Float16)b.w;
        }

        // ---- scores S = Q K^T  (16 tiles across sk2) ----
        f32x4 acc[16];
        #pragma unroll
        for (int t = 0; t < 16; ++t) {
            f16x8 kf = *(const f16x8*)&Klds[(t * 16 + n16) * CC + quad * 8];
            f32x4 z = {0.f, 0.f, 0.f, 0.f};
            acc[t] = __builtin_amdgcn_mfma_f32_16x16x32_f16(qf, kf, z, 0, 0, 0);
        }

        // ---- bias add in C-layout: row = quad*4+r, col = t*16+n16 ----
        if (biasT) {
            const float* bb = biasT + ((size_t)h << 16) + (size_t)(r0 + quad * 4) * LL + n16;
            #pragma unroll
            for (int t = 0; t < 16; ++t)
                #pragma unroll
                for (int r = 0; r < 4; ++r)
                    acc[t][r] += bb[r * LL + t * 16];
        } else {
            const float* bb = bias + h + (size_t)(r0 + quad * 4) * (LL * HH) + n16 * HH;
            #pragma unroll
            for (int t = 0; t < 16; ++t)
                #pragma unroll
                for (int r = 0; r < 4; ++r)
                    acc[t][r] += bb[r * (LL * HH) + t * (16 * HH)];
        }

        // ---- softmax over sk2 (cols), rows live in (quad, reg) ----
        float inv[4];
        #pragma unroll
        for (int r = 0; r < 4; ++r) {
            float m = acc[0][r];
            #pragma unroll
            for (int t = 1; t < 16; ++t) m = fmaxf(m, acc[t][r]);
            m = fmaxf(m, __shfl_xor(m, 1));
            m = fmaxf(m, __shfl_xor(m, 2));
            m = fmaxf(m, __shfl_xor(m, 4));
            m = fmaxf(m, __shfl_xor(m, 8));
            float s = 0.f;
            #pragma unroll
            for (int t = 0; t < 16; ++t) {
                float p = exp2f((acc[t][r] - m) * 1.44269504f);
                acc[t][r] = p;
                s += p;
            }
            s += __shfl_xor(s, 1);
            s += __shfl_xor(s, 2);
            s += __shfl_xor(s, 4);
            s += __shfl_xor(s, 8);
            inv[r] = 1.f / s;
        }

        // ---- P -> LDS (C-layout -> A-layout transpose), per-wave buffer ----
        #pragma unroll
        for (int t = 0; t < 16; ++t)
            #pragma unroll
            for (int r = 0; r < 4; ++r)
                pw[(quad * 4 + r) * P_STRIDE + t * 16 + n16] =
                    (_Float16)(acc[t][r] * inv[r]);

        // ---- O = P V  (K=256 in 8 steps, 2 tiles over c=32) ----
        f32x4 o0 = {0.f, 0.f, 0.f, 0.f}, o1 = {0.f, 0.f, 0.f, 0.f};
        #pragma unroll
        for (int kk = 0; kk < 8; ++kk) {
            f16x8 pf  = *(const f16x8*)&pw[n16 * P_STRIDE + kk * 32 + quad * 8];
            f16x8 vf0 = *(const f16x8*)&Vt[n16 * VT_STRIDE + kk * 32 + quad * 8];
            f16x8 vf1 = *(const f16x8*)&Vt[(16 + n16) * VT_STRIDE + kk * 32 + quad * 8];
            o0 = __builtin_amdgcn_mfma_f32_16x16x32_f16(pf, vf0, o0, 0, 0, 0);
            o1 = __builtin_amdgcn_mfma_f32_16x16x32_f16(pf, vf1, o1, 0, 0, 0);
        }

        // ---- gate + store (C-layout: row = quad*4+r, col = tile*16+n16) ----
        #pragma unroll
        for (int r = 0; r < 4; ++r) {
            const int s2 = r0 + quad * 4 + r;
            const float g0 = gateb[(s2 * CC + n16) * HH];
            const float g1 = gateb[(s2 * CC + 16 + n16) * HH];
            ob[(size_t)s2 * CC + n16]      = o0[r] * g0;
            ob[(size_t)s2 * CC + 16 + n16] = o1[r] * g1;
        }
    }
}

extern "C" void kernel_launch(void* const* d_in, const int* in_sizes, int n_in,
                              void* d_out, int out_size, void* d_ws, size_t ws_size,
                              hipStream_t stream) {
    const float* q    = (const float*)d_in[0];
    const float* k    = (const float*)d_in[1];
    const float* v    = (const float*)d_in[2];
    const float* bias = (const float*)d_in[3];
    const float* gate = (const float*)d_in[4];
    float* out = (float*)d_out;

    float* biasT = nullptr;
    if (ws_size >= (size_t)HH * LL * LL * sizeof(float)) {
        biasT = (float*)d_ws;
        bias_transpose<<<dim3((HH * LL * LL) / 256), 256, 0, stream>>>(bias, biasT);
    }
    dim3 grid(LL, HH);
    triattn<<<grid, 256, 0, stream>>>(q, k, v, bias, biasT, gate, out);
}